// Round 7
// baseline (2561.178 us; speedup 1.0000x reference)
//
#include <hip/hip_runtime.h>
#include <hip/hip_cooperative_groups.h>

// Tree-GRU encoder, round 7.
//  - Recurrent loop never touches the 129MB `out` buffer: DT pass writes
//    compact Hfd[g] (bf16), TD writes Htd[g]; a finalize kernel streams the
//    compact buffers to `out` once (coalesced + nontemporal). Loop working set
//    (Xc+Hdt+Hfd+Htd+wt ~140MB) stays LLC-resident.
//  - 32x32x16 MFMA, BM=256 x BN=64 h-cols per block, wave=64x32 (acc 128 VGPR),
//    weights streamed per K-chunk into LDS (no weight residency).
//  - K-chunks processed in rotated order ending at chunk cg so the epilogue's
//    hprev (H[g][col], col in chunk cg) is still in the Ah LDS buffer.
//  - LDS 112KB single-buffered (Ax 32K | Ah 32K | B 48K), 2 barriers/chunk,
//    register prefetch of the next chunk.
//
// ws: wt bf16 4x[1536][512] | Xc bf16[NG][512] | Hdt bf16[NG][512] | zrow[512]
//     | Hfd bf16[NG][512] | Htd bf16[NG][512] | sched/meta/gidx/pslot (i32)

#define NL 256
#define NB 128
#define NH 512
#define NG (NB * NL)

typedef short short8 __attribute__((ext_vector_type(8)));
typedef float f32x4 __attribute__((ext_vector_type(4)));
typedef float f32x16 __attribute__((ext_vector_type(16)));

__device__ __forceinline__ float bf2f(unsigned short u) {
  union { unsigned int i; float f; } c; c.i = ((unsigned int)u) << 16; return c.f;
}
__device__ __forceinline__ unsigned short f2bf(float f) {
  union { float f; unsigned int i; } c; c.f = f;
  return (unsigned short)((c.i + 0x7FFFu + ((c.i >> 16) & 1u)) >> 16);  // RNE
}
__device__ __forceinline__ short8 pk_bf16(f32x4 a, f32x4 b) {
  union { unsigned int u[4]; short8 s; } r;
  asm("v_cvt_pk_bf16_f32 %0, %1, %2" : "=v"(r.u[0]) : "v"(a[0]), "v"(a[1]));
  asm("v_cvt_pk_bf16_f32 %0, %1, %2" : "=v"(r.u[1]) : "v"(a[2]), "v"(a[3]));
  asm("v_cvt_pk_bf16_f32 %0, %1, %2" : "=v"(r.u[2]) : "v"(b[0]), "v"(b[1]));
  asm("v_cvt_pk_bf16_f32 %0, %1, %2" : "=v"(r.u[3]) : "v"(b[2]), "v"(b[3]));
  return r.s;
}
__device__ __forceinline__ void atom_pk_bf16(unsigned short* p, unsigned int ud) {
  asm volatile("global_atomic_pk_add_bf16 %0, %1, off" :: "v"((void*)p), "v"(ud) : "memory");
}

// ---- prep: 4 weight matrices [512][1536] f32 -> transposed [1536][512] bf16 ----
__global__ void prep_wt4(const float* __restrict__ w0, const float* __restrict__ w1,
                         const float* __restrict__ w2, const float* __restrict__ w3,
                         unsigned short* __restrict__ wt) {
  __shared__ float t[32][33];
  const float* w = blockIdx.z == 0 ? w0 : blockIdx.z == 1 ? w1 : blockIdx.z == 2 ? w2 : w3;
  unsigned short* dst = wt + (size_t)blockIdx.z * 1536 * 512;
  int n0 = blockIdx.x * 32, k0 = blockIdx.y * 32;
  int tx = threadIdx.x & 31, ty = threadIdx.x >> 5;
  #pragma unroll
  for (int i = 0; i < 4; ++i)
    t[ty + 8 * i][tx] = w[(size_t)(k0 + ty + 8 * i) * 1536 + n0 + tx];
  __syncthreads();
  #pragma unroll
  for (int i = 0; i < 4; ++i)
    dst[(size_t)(n0 + ty + 8 * i) * 512 + k0 + tx] = f2bf(t[tx][ty + 8 * i]);
}

// ---- prep: depths, level buckets, slots, parent slots (1 block, 256 thr) ----
__global__ void prep_sched(const int* __restrict__ td_pidx,
                           const float* __restrict__ td_pval,
                           int* __restrict__ sched, int* __restrict__ meta,
                           int* __restrict__ gidx, int* __restrict__ pslot) {
  __shared__ unsigned char dep[NB][NL];
  __shared__ unsigned short cnb[NB][256];
  __shared__ int cnt[256];
  __shared__ int off[257];
  __shared__ int dmax_s;
  const int tid = threadIdx.x;
  for (int j = tid; j < NB * 256; j += 256) ((unsigned short*)cnb)[j] = 0;
  if (tid == 0) dmax_s = 0;
  __syncthreads();
  if (tid < NB) {
    int b = tid, lmax = 0;
    for (int i = 0; i < NL; ++i) {
      float pv = td_pval[i * NB + b];
      int pi = td_pidx[i * NB + b];
      int d = (pv != 0.f) ? (int)dep[b][pi] + 1 : 0;   // head[i] < i
      dep[b][i] = (unsigned char)d;
      cnb[b][d]++;
      lmax = max(lmax, d);
    }
    atomicMax(&dmax_s, lmax);
  }
  __syncthreads();
  {
    int s = 0;
    for (int b = 0; b < NB; ++b) s += cnb[b][tid];
    cnt[tid] = s;
  }
  __syncthreads();
  if (tid == 0) {
    int s = 0;
    for (int d = 0; d < 256; ++d) { off[d] = s; s += cnt[d]; }
    off[256] = s;
  }
  __syncthreads();
  {
    int run = off[tid];
    for (int b = 0; b < NB; ++b) {
      int t = cnb[b][tid];
      cnb[b][tid] = (unsigned short)run;
      run += t;
    }
  }
  __syncthreads();
  if (tid < NB) {
    int b = tid;
    for (int i = 0; i < NL; ++i) {
      float pv = td_pval[i * NB + b];
      int pi = td_pidx[i * NB + b];
      int d = dep[b][i];
      int g = cnb[b][d]++;
      sched[g] = (b << 8) | i;
      gidx[b * NL + i] = g;
      pslot[g] = (pv != 0.f) ? gidx[b * NL + pi] : -1;
    }
  }
  if (tid == 0) meta[0] = dmax_s;
  __syncthreads();
  meta[1 + tid] = off[tid];
  meta[257 + tid] = cnt[tid];
}

// ---- prep: gather emb rows into slot order, f32 -> bf16 ----
__global__ void prep_xc(const float* __restrict__ emb, const int* __restrict__ sched,
                        unsigned short* __restrict__ Xc) {
  int g = blockIdx.x * 4 + (threadIdx.x >> 6);
  int lane = threadIdx.x & 63;
  int e = sched[g];
  int b = e >> 8, node = e & 255;
  const float* src = emb + ((size_t)node * NB + b) * 512 + lane * 8;
  f32x4 v0 = *(const f32x4*)src;
  f32x4 v1 = *(const f32x4*)(src + 4);
  *(short8*)(Xc + (size_t)g * 512 + lane * 8) = pk_bf16(v0, v1);
}

// ---- main cooperative kernel ----
// grid = 256 x 512 thr (8 waves, 1 block/CU). bi: pass=bi>>7, rp=(bi>>3)&15, cg=bi&7.
// Block tile: 256 rows x 64 h-cols. Wave (wr=w>>1, wc=w&1): 64 rows x 32 cols.
__launch_bounds__(512, 2)
__global__ void tree_gru(const float* __restrict__ dt_b,
                         const float* __restrict__ td_b,
                         const unsigned short* __restrict__ wt,
                         const unsigned short* __restrict__ Xc,
                         unsigned short* __restrict__ Hdt,
                         unsigned short* __restrict__ Hfd,
                         unsigned short* __restrict__ Htd,
                         const unsigned short* __restrict__ zrow,
                         const int* __restrict__ meta,
                         const int* __restrict__ pslot) {
  extern __shared__ unsigned char lds[];
  unsigned char* Axb = lds;             // 32 KB [256 rows][128B] swizzled
  unsigned char* Ahb = lds + 32768;     // 32 KB
  unsigned char* Bwb = lds + 65536;     // 48 KB [384 nrows][128B] swizzled
  const int tid = threadIdx.x;
  const int bi  = blockIdx.x;
  const int pass = bi >> 7;             // 0 = DT bottom-up, 1 = TD top-down
  const int rp   = (bi >> 3) & 15;
  const int cg   = bi & 7;              // 64-col tile
  const int w = tid >> 6, l = tid & 63;
  const int wr = w >> 1, wc = w & 1;
  const int l31 = l & 31, lh = l >> 5;
  const int col = cg * 64 + wc * 32 + l31;
  const float* bias = pass ? td_b : dt_b;
  const float br = bias[col], bz = bias[NH + col], bn = bias[2 * NH + col];

  // B staging constants: thread covers words j = tid + 512*i (16B each)
  const unsigned short* bsrc[6];
  int bdst[6];
  #pragma unroll
  for (int i = 0; i < 6; ++i) {
    int j = tid + 512 * i;
    int nrow = j >> 3, slot = j & 7;
    int s = nrow >> 6, n = nrow & 63;
    int side = (s >= 3) ? 1 : 0;
    int gate = s - side * 3;
    bsrc[i] = wt + (size_t)(pass * 2 + side) * (1536 * 512)
                 + (size_t)(gate * 512 + cg * 64 + n) * 512 + slot * 8;
    bdst[i] = nrow * 128 + ((slot * 16) ^ ((nrow & 7) << 4));
  }
  const int srow = tid >> 1;            // A staging: 2 thr/row, 64B halves
  const int sh64 = (tid & 1) * 64;      // byte offset of half within 128B
  const int sdswz = (srow & 7) << 4;
  const int rsw = (l31 & 7) << 4;

  cooperative_groups::grid_group grid = cooperative_groups::this_grid();
  const int Dmax = meta[0];

  for (int p = 0; p <= Dmax; ++p) {
    const int d = pass ? p : (Dmax - p);
    const int off_d = meta[1 + d];
    const int cnt_d = meta[257 + d];
    const int T = (cnt_d + 255) >> 8;
    for (int t = rp; t < T; t += 16) {
      const int g0 = off_d + t * 256;
      const int rows = min(256, cnt_d - t * 256);
      const int gg = g0 + min(srow, rows - 1);
      const unsigned short* sxp = Xc + (size_t)gg * 512 + (tid & 1) * 32;
      const unsigned short* shp;
      if (pass == 0) {
        shp = Hdt + (size_t)gg * 512 + (tid & 1) * 32;
      } else {
        int ps = pslot[gg];
        shp = (ps >= 0 ? Htd + (size_t)ps * 512 : zrow) + (tid & 1) * 32;
      }
      short8 rx[4], rh[4], rb[6];
      const int c0 = (cg + 1) & 7;      // rotated chunk order ends at chunk cg
      #pragma unroll
      for (int jj = 0; jj < 4; ++jj) {
        rx[jj] = *(const short8*)(sxp + c0 * 64 + jj * 8);
        rh[jj] = *(const short8*)(shp + c0 * 64 + jj * 8);
      }
      #pragma unroll
      for (int i = 0; i < 6; ++i) rb[i] = *(const short8*)(bsrc[i] + c0 * 64);

      f32x16 aR[2], aZ[2], aXN[2], aHN[2];
      #pragma unroll
      for (int rf = 0; rf < 2; ++rf) {
        #pragma unroll
        for (int e = 0; e < 16; ++e) { aR[rf][e] = 0.f; aZ[rf][e] = 0.f; aXN[rf][e] = 0.f; aHN[rf][e] = 0.f; }
      }

      for (int ci = 0; ci < 8; ++ci) {
        const int kb0 = ((cg + 1 + ci) & 7) * 0;  // (chunk id only matters for loads)
        (void)kb0;
        __syncthreads();                 // prev chunk fully consumed
        #pragma unroll
        for (int jj = 0; jj < 4; ++jj) {
          *(short8*)(Axb + srow * 128 + ((sh64 + jj * 16) ^ sdswz)) = rx[jj];
          *(short8*)(Ahb + srow * 128 + ((sh64 + jj * 16) ^ sdswz)) = rh[jj];
        }
        #pragma unroll
        for (int i = 0; i < 6; ++i) *(short8*)(Bwb + bdst[i]) = rb[i];
        if (ci < 7) {
          const int cn = (cg + 2 + ci) & 7;
          #pragma unroll
          for (int jj = 0; jj < 4; ++jj) {
            rx[jj] = *(const short8*)(sxp + cn * 64 + jj * 8);
            rh[jj] = *(const short8*)(shp + cn * 64 + jj * 8);
          }
          #pragma unroll
          for (int i = 0; i < 6; ++i) rb[i] = *(const short8*)(bsrc[i] + cn * 64);
        }
        __syncthreads();                 // chunk visible
        #pragma unroll
        for (int ks = 0; ks < 4; ++ks) {
          const int kb = (ks * 32 + lh * 16) ^ rsw;
          short8 ax0 = *(const short8*)(Axb + (wr * 64 + l31) * 128 + kb);
          short8 ax1 = *(const short8*)(Axb + (wr * 64 + 32 + l31) * 128 + kb);
          short8 ah0 = *(const short8*)(Ahb + (wr * 64 + l31) * 128 + kb);
          short8 ah1 = *(const short8*)(Ahb + (wr * 64 + 32 + l31) * 128 + kb);
          short8 b0 = *(const short8*)(Bwb + (0 * 64 + wc * 32 + l31) * 128 + kb);
          short8 b1 = *(const short8*)(Bwb + (1 * 64 + wc * 32 + l31) * 128 + kb);
          short8 b2 = *(const short8*)(Bwb + (2 * 64 + wc * 32 + l31) * 128 + kb);
          short8 b3 = *(const short8*)(Bwb + (3 * 64 + wc * 32 + l31) * 128 + kb);
          short8 b4 = *(const short8*)(Bwb + (4 * 64 + wc * 32 + l31) * 128 + kb);
          short8 b5 = *(const short8*)(Bwb + (5 * 64 + wc * 32 + l31) * 128 + kb);
          aR[0]  = __builtin_amdgcn_mfma_f32_32x32x16_bf16(ax0, b0, aR[0], 0, 0, 0);
          aR[1]  = __builtin_amdgcn_mfma_f32_32x32x16_bf16(ax1, b0, aR[1], 0, 0, 0);
          aZ[0]  = __builtin_amdgcn_mfma_f32_32x32x16_bf16(ax0, b1, aZ[0], 0, 0, 0);
          aZ[1]  = __builtin_amdgcn_mfma_f32_32x32x16_bf16(ax1, b1, aZ[1], 0, 0, 0);
          aXN[0] = __builtin_amdgcn_mfma_f32_32x32x16_bf16(ax0, b2, aXN[0], 0, 0, 0);
          aXN[1] = __builtin_amdgcn_mfma_f32_32x32x16_bf16(ax1, b2, aXN[1], 0, 0, 0);
          aR[0]  = __builtin_amdgcn_mfma_f32_32x32x16_bf16(ah0, b3, aR[0], 0, 0, 0);
          aR[1]  = __builtin_amdgcn_mfma_f32_32x32x16_bf16(ah1, b3, aR[1], 0, 0, 0);
          aZ[0]  = __builtin_amdgcn_mfma_f32_32x32x16_bf16(ah0, b4, aZ[0], 0, 0, 0);
          aZ[1]  = __builtin_amdgcn_mfma_f32_32x32x16_bf16(ah1, b4, aZ[1], 0, 0, 0);
          aHN[0] = __builtin_amdgcn_mfma_f32_32x32x16_bf16(ah0, b5, aHN[0], 0, 0, 0);
          aHN[1] = __builtin_amdgcn_mfma_f32_32x32x16_bf16(ah1, b5, aHN[1], 0, 0, 0);
        }
      }
      // epilogue: Ahb holds chunk cg -> hprev = H[g][col] straight from LDS.
      // C/D 32x32 layout: col = l&31, row = (reg&3) + 8*(reg>>2) + 4*(l>>5).
      #pragma unroll
      for (int rf = 0; rf < 2; ++rf) {
        #pragma unroll
        for (int reg = 0; reg < 16; ++reg) {
          const int row = wr * 64 + rf * 32 + (reg & 3) + 8 * (reg >> 2) + 4 * lh;
          if (row < rows) {
            const int g = g0 + row;
            const int hb = row * 128 + ((2 * (wc * 32 + l31)) ^ ((row & 7) << 4));
            const float hprev = bf2f(*(const unsigned short*)(Ahb + hb));
            float rr = 1.f / (1.f + __expf(-(aR[rf][reg] + br)));
            float zz = 1.f / (1.f + __expf(-(aZ[rf][reg] + bz)));
            float e2 = __expf(2.f * (aXN[rf][reg] + bn + rr * aHN[rf][reg]));
            float nn = (e2 - 1.f) / (e2 + 1.f);          // tanh
            float h = (1.f - zz) * nn + zz * hprev;
            float ho = __shfl_xor(h, 1);
            if (!(l & 1)) {
              unsigned int ud;
              asm("v_cvt_pk_bf16_f32 %0, %1, %2" : "=v"(ud) : "v"(h), "v"(ho));
              if (pass == 0) {
                *(unsigned int*)(Hfd + (size_t)g * 512 + col) = ud;
                int ps = pslot[g];
                if (ps >= 0) atom_pk_bf16(Hdt + (size_t)ps * 512 + col, ud);
              } else {
                *(unsigned int*)(Htd + (size_t)g * 512 + col) = ud;
              }
            }
          }
        }
      }
    }
    grid.sync();
  }
}

// ---- finalize: compact Hfd/Htd -> out [B][L][1024] f32 + out_t root rows ----
__global__ void finalize(const unsigned short* __restrict__ Hfd,
                         const unsigned short* __restrict__ Htd,
                         const int* __restrict__ sched,
                         const int* __restrict__ root_index,
                         float* __restrict__ out) {
  const int g = blockIdx.x * 16 + (threadIdx.x >> 4);
  const int part = threadIdx.x & 15;     // 16 thr per g, 32 elems per half each
  const int e = sched[g];
  const int b = e >> 8, node = e & 255;
  float* dst = out + ((size_t)b * NL + node) * 1024;
  const bool isroot = (node == root_index[b]);
  float* dst2 = out + (size_t)NB * NL * 1024 + (size_t)b * 1024;
  const unsigned short* s1 = Hfd + (size_t)g * 512 + part * 32;
  const unsigned short* s2 = Htd + (size_t)g * 512 + part * 32;
  #pragma unroll
  for (int half = 0; half < 2; ++half) {
    const unsigned short* s = half ? s2 : s1;
    const int o = half * 512 + part * 32;
    #pragma unroll
    for (int j = 0; j < 4; ++j) {
      short8 v = *(const short8*)(s + j * 8);
      f32x4 lo, hi;
      #pragma unroll
      for (int q = 0; q < 4; ++q) {
        lo[q] = bf2f((unsigned short)v[q]);
        hi[q] = bf2f((unsigned short)v[4 + q]);
      }
      __builtin_nontemporal_store(lo, (f32x4*)(dst + o + j * 8));
      __builtin_nontemporal_store(hi, (f32x4*)(dst + o + j * 8 + 4));
      if (isroot) {
        *(f32x4*)(dst2 + o + j * 8) = lo;
        *(f32x4*)(dst2 + o + j * 8 + 4) = hi;
      }
    }
  }
}

extern "C" void kernel_launch(void* const* d_in, const int* in_sizes, int n_in,
                              void* d_out, int out_size, void* d_ws, size_t ws_size,
                              hipStream_t stream) {
  (void)in_sizes; (void)n_in; (void)out_size; (void)ws_size;
  const float* emb      = (const float*)d_in[0];
  const int*   td_pidx  = (const int*)d_in[4];
  const float* td_pval  = (const float*)d_in[5];
  const int*   root_idx = (const int*)d_in[6];
  const float* dt_Wx    = (const float*)d_in[7];
  const float* dt_Uh    = (const float*)d_in[8];
  const float* dt_b     = (const float*)d_in[9];
  const float* td_Wx    = (const float*)d_in[10];
  const float* td_Uh    = (const float*)d_in[11];
  const float* td_b     = (const float*)d_in[12];
  float* out = (float*)d_out;

  unsigned short* wt   = (unsigned short*)d_ws;
  unsigned short* Xc   = wt + (size_t)4 * 1536 * 512;
  unsigned short* Hdt  = Xc + (size_t)NG * NH;
  unsigned short* zrow = Hdt + (size_t)NG * NH;
  unsigned short* Hfd  = zrow + NH;
  unsigned short* Htd  = Hfd + (size_t)NG * NH;
  int* sched = (int*)(Htd + (size_t)NG * NH);
  int* meta  = sched + NG;
  int* gidx  = meta + 520;
  int* pslot = gidx + NG;

  (void)hipMemsetAsync(Hdt, 0, ((size_t)NG * NH + NH) * 2, stream);  // Hdt + zrow
  prep_wt4<<<dim3(48, 16, 4), dim3(256), 0, stream>>>(dt_Wx, dt_Uh, td_Wx, td_Uh, wt);
  prep_sched<<<dim3(1), dim3(256), 0, stream>>>(td_pidx, td_pval, sched, meta, gidx, pslot);
  prep_xc<<<dim3(NG / 4), dim3(256), 0, stream>>>(emb, sched, Xc);

  (void)hipFuncSetAttribute((const void*)tree_gru,
                            hipFuncAttributeMaxDynamicSharedMemorySize, 114688);

  void* args[] = {
    (void*)&dt_b, (void*)&td_b, (void*)&wt, (void*)&Xc, (void*)&Hdt, (void*)&Hfd,
    (void*)&Htd, (void*)&zrow, (void*)&meta, (void*)&pslot
  };
  (void)hipLaunchCooperativeKernel((const void*)tree_gru, dim3(256), dim3(512),
                                   args, 114688u, stream);
  finalize<<<dim3(NG / 16), dim3(256), 0, stream>>>(Hfd, Htd, sched, root_idx, out);
}